// Round 10
// baseline (420.576 us; speedup 1.0000x reference)
//
#include <hip/hip_runtime.h>
#include <hip/hip_bf16.h>

// B=2, H=16, S=2048, D=64, DMODEL=1024
// Round 20: r19 refuted the LDS-traffic theory (halved traffic, 8 waves/CU,
// 68us). Assembled data: 8 w/CU=68, 16 w/CU=52-55 (every geometry), TLP is
// the binding constraint; traffic/barrier tweaks are +-6%. Unexplored: 32
// w/CU with the PROVEN dbuf/1-barrier shape (r14's 32-wave try was sbuf
// lockstep). Occupancy cliff: 8 waves/SIMD needs VGPR<=64. Design: 1024-thr
// blocks, 16 waves = qg{0..3}x32q x kh{0..3}x32kv, QBLK=128 KVBLK=128 dbuf
// (71,680B -> 2 blocks/CU = 32 waves/CU), __launch_bounds__(1024,8) forcing
// VGPR<=64. To fit: NO register prefetch -- stage loads issue in the stage
// phase; their ~200cyc L2 latency is what 2x TLP exists to cover (m114).
// Per-wave state qf16+O32+w8 = r17's budget (which compiled to 64).
// kh 4-way epilogue = staged pair tree (r14-proven), +~1us of syncs.
// convert_vw / tiled proj unchanged.

typedef float  f32x16 __attribute__((ext_vector_type(16)));
typedef float  f32x4v __attribute__((ext_vector_type(4)));
typedef float  f32x2v __attribute__((ext_vector_type(2)));
typedef __bf16 bf16x8 __attribute__((ext_vector_type(8)));
typedef __bf16 bf16x4 __attribute__((ext_vector_type(4)));
typedef __bf16 bf16x2 __attribute__((ext_vector_type(2)));

static constexpr int Bn = 2, Hn = 16, Sn = 2048, Dn = 64, DM = 1024;
static constexpr size_t QKV_ELEMS = (size_t)Bn * Hn * Sn * Dn;   // 4,194,304

#define QSCALE 0.18033688011112042f   // 0.125 * log2(e)

#define LGKM_BARRIER() do {                                  \
    asm volatile("s_waitcnt lgkmcnt(0)" ::: "memory");       \
    __builtin_amdgcn_s_barrier();                            \
  } while (0)

#if __has_builtin(__builtin_amdgcn_cvt_pk_bf16_f32)
static __device__ __forceinline__ unsigned pack2(float a, float b) {
  bf16x2 t = __builtin_amdgcn_cvt_pk_bf16_f32(a, b);
  union { bf16x2 v; unsigned u; } c; c.v = t; return c.u;
}
#else
static __device__ __forceinline__ unsigned pack2(float a, float b) {
  union { __bf16 h; unsigned short s; } ua, ub;
  ua.h = (__bf16)a; ub.h = (__bf16)b;
  return (unsigned)ua.s | ((unsigned)ub.s << 16);
}
#endif

static __device__ __forceinline__ void unzip8(const unsigned* wds, bf16x8* r0, bf16x8* r1) {
  union { unsigned u[4]; bf16x8 v; } a, b;
#pragma unroll
  for (int i = 0; i < 4; ++i) {
    unsigned lo = wds[2 * i], hi = wds[2 * i + 1];
    a.u[i] = (lo & 0xffffu) | (hi << 16);
    b.u[i] = (lo >> 16) | (hi & 0xffff0000u);
  }
  *r0 = a.v; *r1 = b.v;
}

// ------------------------------------------------- V-T + W-T converts only
// [0,1024) V-T; [1024,1280) W-T (tiled frag layout). K fused into attn.
__global__ __launch_bounds__(256) void convert_vw(
    const float* __restrict__ v, const float* __restrict__ w,
    __bf16* __restrict__ vt, __bf16* __restrict__ wt) {
  __shared__ __bf16 T[64][74];
  const int bid = blockIdx.x, t = threadIdx.x;

  const float* s0;
  __bf16* dst0 = nullptr;
  int nt_ = 0, kt_ = 0;
  const bool isW = (bid >= 1024);
  {
    const int r = t >> 2, c0 = (t & 3) * 16;
    if (!isW) {
      const int idx = bid;
      const int kv0 = (idx & 31) * 64, bh = idx >> 5;
      s0 = v + ((size_t)bh * Sn + kv0 + r) * Dn + c0;
      dst0 = vt + (size_t)bh * Dn * Sn + kv0;
    } else {
      const int idx = bid - 1024;
      nt_ = (idx & 15) * 64; kt_ = (idx >> 4) * 64;
      s0 = w + (size_t)(kt_ + r) * DM + nt_ + c0;
    }
    union { bf16x8 v8; unsigned u[4]; } o0, o1;
#pragma unroll
    for (int i = 0; i < 2; ++i) {
      f32x4v f = *(const f32x4v*)(s0 + i * 4);
#pragma unroll
      for (int j = 0; j < 4; ++j) o0.v8[i * 4 + j] = (__bf16)f[j];
    }
#pragma unroll
    for (int i = 0; i < 2; ++i) {
      f32x4v f = *(const f32x4v*)(s0 + 8 + i * 4);
#pragma unroll
      for (int j = 0; j < 4; ++j) o1.v8[i * 4 + j] = (__bf16)f[j];
    }
#pragma unroll
    for (int j = 0; j < 4; ++j) {
      *(unsigned*)&T[r][c0 + 2 * j]     = o0.u[j];
      *(unsigned*)&T[r][c0 + 8 + 2 * j] = o1.u[j];
    }
  }
  __syncthreads();
  const int rp = t >> 3, k0 = (t & 7) * 8;
  unsigned wds[8];
#pragma unroll
  for (int i = 0; i < 8; ++i) wds[i] = *(const unsigned*)&T[k0 + i][2 * rp];
  bf16x8 r0, r1; unzip8(wds, &r0, &r1);
  if (!isW) {
    __bf16* d0 = dst0 + (size_t)(2 * rp) * Sn + k0;
    *(bf16x8*)d0 = r0;
    *(bf16x8*)(d0 + Sn) = r1;
  } else {
    const int n0 = nt_ + 2 * rp;              // even
    __bf16* d0 = wt + ((size_t)(n0 >> 5) * 128 + (kt_ >> 3) + (t & 7)) * 256
                    + (n0 & 31) * 8;
    *(bf16x8*)d0 = r0;                        // row n0
    *(bf16x8*)(d0 + 8) = r1;                  // row n0+1 (same tile, +16B)
  }
}

// ---------------------------------------------------------------- attention
// 512 blocks (XCD-chunked), 1024 thr = 16 waves = qg{0..3}(32q) x
// kh{0..3}(32kv of KVBLK=128). NT=16, dbuf, 1 lgkm-barrier/iter, no reg
// prefetch (stage loads in-phase; 32 waves/CU cover the L2 latency).
// K read fp32 + converted in-register during staging.
__global__ __launch_bounds__(1024, 8) void attn(
    const float* __restrict__ Qf, const float* __restrict__ Kf,
    const __bf16* __restrict__ Vtg, __bf16* __restrict__ Cc) {
  __shared__ __align__(16) unsigned char lds[71680];
  __bf16 (*Ks)[128][72]  = (__bf16 (*)[128][72])lds;           // [2][128][72]
  __bf16 (*Vs)[64][136]  = (__bf16 (*)[64][136])(lds + 36864); // [2][64][136]

  const int tid = threadIdx.x;
  const int wave = tid >> 6, lane = tid & 63;
  const int ln = lane & 31, g = lane >> 5;
  const int qg = wave >> 2, kh = wave & 3;
  const int f = blockIdx.x;
  const int swz = (f & 7) * 64 + (f >> 3);
  const int qb = swz & 15, h = (swz >> 4) & 15, bz = swz >> 8;

  const size_t hoff = (size_t)(bz * Hn + h) * Sn * Dn;
  const float*  Qp = Qf + hoff + (size_t)(qb * 128 + qg * 32) * Dn;
  const float*  Kp = Kf + hoff;      // fp32 [kv][d]
  const __bf16* Vp = Vtg + hoff;     // bf16 [d][kv]

  // Q A-fragments: fp32 load + scale + cvt (prologue only)
  bf16x8 qf[4];
#pragma unroll
  for (int ks = 0; ks < 4; ++ks) {
    const float* qp = Qp + (size_t)ln * Dn + ks * 16 + g * 8;
    f32x4v f0 = *(const f32x4v*)qp;
    f32x4v f1 = *(const f32x4v*)(qp + 4);
#pragma unroll
    for (int j = 0; j < 4; ++j) {
      qf[ks][j]     = (__bf16)(f0[j] * QSCALE);
      qf[ks][4 + j] = (__bf16)(f1[j] * QSCALE);
    }
  }

  // staging maps (1024 thr): K [128 kv][64 d] 8 fp32/thread;
  // V [64 d][128 kv] 8 bf16/thread, permuted write (2x b64).
  const int kr = tid >> 3, kc = (tid & 7) * 8;
  const int vr = tid >> 4, vc = (tid & 15) * 8;
  const float*  kbase = Kp + (size_t)kr * Dn + kc;
  const __bf16* vbase = Vp + (size_t)vr * Sn + vc;
  // permuted 16-block slot: slots{0-3}=orig{0-3}, {4-7}=orig{8-11},
  // {8-11}=orig{4-7}, {12-15}=orig{12-15}
  const int voff = (vc >> 4) * 16 + ((vc & 8) ? 4 : 0);

#define STAGE(b, t) do {                                          \
    const float* kp_ = kbase + (size_t)(t) * 128 * Dn;            \
    f32x4v a0_ = *(const f32x4v*)kp_;                             \
    f32x4v a1_ = *(const f32x4v*)(kp_ + 4);                       \
    bf16x8 vl_ = *(const bf16x8*)(vbase + (t) * 128);             \
    bf16x8 kx_;                                                   \
    _Pragma("unroll")                                             \
    for (int j_ = 0; j_ < 4; ++j_) {                              \
      kx_[j_] = (__bf16)a0_[j_]; kx_[4 + j_] = (__bf16)a1_[j_];   \
    }                                                             \
    *(bf16x8*)&Ks[b][kr][kc] = kx_;                               \
    union { bf16x8 v; bf16x4 h[2]; } uv_; uv_.v = vl_;            \
    *(bf16x4*)&Vs[b][vr][voff]     = uv_.h[0];                    \
    *(bf16x4*)&Vs[b][vr][voff + 8] = uv_.h[1];                    \
  } while (0)

  STAGE(0, 0);
  LGKM_BARRIER();

  f32x16 O0 = {}, O1 = {};                   // O^T halves: d [0,32),[32,64)
  float Lown = 0.0f;
  constexpr int NT = Sn / 128;               // 16

  for (int kt = 0; kt < NT; ++kt) {
    const int buf = kt & 1;

    // QK^T over this wave's 32-kv quarter
    bf16x8 kf[4];
#pragma unroll
    for (int ks = 0; ks < 4; ++ks)
      kf[ks] = *(const bf16x8*)&Ks[buf][kh * 32 + ln][ks * 16 + g * 8];
    f32x16 s = {};
    __builtin_amdgcn_s_setprio(1);
#pragma unroll
    for (int ks = 0; ks < 4; ++ks)
      s = __builtin_amdgcn_mfma_f32_32x32x16_bf16(kf[ks], qf[ks], s, 0, 0, 0);
    __builtin_amdgcn_s_setprio(0);

    // softmax-exp + pack
    float p[16];
#pragma unroll
    for (int r = 0; r < 16; ++r) p[r] = __builtin_amdgcn_exp2f(s[r]);
    f32x2v s2 = {0.0f, 0.0f};
#pragma unroll
    for (int tt = 0; tt < 8; ++tt) { f32x2v t2 = {p[2 * tt], p[2 * tt + 1]}; s2 += t2; }
    Lown += s2[0] + s2[1];
    unsigned w[8];
#pragma unroll
    for (int tt = 0; tt < 8; ++tt) w[tt] = pack2(p[2 * tt], p[2 * tt + 1]);

    // PV over the 32-kv quarter: permuted V^T gives contiguous b128 frags
    __builtin_amdgcn_s_setprio(1);
#pragma unroll
    for (int s4 = 0; s4 < 2; ++s4) {
      const int cb = kh * 32 + s4 * 16 + g * 8;
      bf16x8 vf0 = *(const bf16x8*)&Vs[buf][ln][cb];
      bf16x8 vf1 = *(const bf16x8*)&Vs[buf][32 + ln][cb];
      union { unsigned u[4]; bf16x8 v; } pu;
      pu.u[0] = w[s4 * 4 + 0];
      pu.u[1] = w[s4 * 4 + 1];
      pu.u[2] = w[s4 * 4 + 2];
      pu.u[3] = w[s4 * 4 + 3];
      O0 = __builtin_amdgcn_mfma_f32_32x32x16_bf16(vf0, pu.v, O0, 0, 0, 0);
      O1 = __builtin_amdgcn_mfma_f32_32x32x16_bf16(vf1, pu.v, O1, 0, 0, 0);
    }
    __builtin_amdgcn_s_setprio(0);

    // stage next tile (loads issue here; TLP covers the L2 latency)
    if (kt + 1 < NT) STAGE(buf ^ 1, kt + 1);

    LGKM_BARRIER();
  }

  // ---- kh 4-way O/L reduction: staged pair tree; normalize; store ----
  float Lred = Lown + __shfl_xor(Lown, 32);  // merge g halves (same q col)
  float* Ex = (float*)lds;                   // 512 slots x 32 f32 = 65,536 B
  float* Lx = (float*)(lds + 65536);         // 512 f32 = 2,048 B
  // stage A (parallel pairs): kh {1,3} -> {0,2}
  {
    const int idx = ((qg << 1) | (kh >> 1)) * 64 + lane;   // 0..511
    const int sl = idx * 32;
    if (kh & 1) {
#pragma unroll
      for (int i = 0; i < 4; ++i) {
        f32x4v t = {O0[4 * i], O0[4 * i + 1], O0[4 * i + 2], O0[4 * i + 3]};
        *(f32x4v*)&Ex[sl + 4 * i] = t;
      }
#pragma unroll
      for (int i = 0; i < 4; ++i) {
        f32x4v t = {O1[4 * i], O1[4 * i + 1], O1[4 * i + 2], O1[4 * i + 3]};
        *(f32x4v*)&Ex[sl + 16 + 4 * i] = t;
      }
      Lx[idx] = Lred;
    }
    __syncthreads();
    if (!(kh & 1)) {
#pragma unroll
      for (int i = 0; i < 4; ++i) {
        f32x4v t = *(const f32x4v*)&Ex[sl + 4 * i];
#pragma unroll
        for (int c = 0; c < 4; ++c) O0[4 * i + c] += t[c];
      }
#pragma unroll
      for (int i = 0; i < 4; ++i) {
        f32x4v t = *(const f32x4v*)&Ex[sl + 16 + 4 * i];
#pragma unroll
        for (int c = 0; c < 4; ++c) O1[4 * i + c] += t[c];
      }
      Lred += Lx[idx];
    }
    __syncthreads();
  }
  // stage B: kh 2 -> kh 0
  float inv = 0.0f;
  {
    const int idx = qg * 64 + lane;          // 0..255
    const int sl = idx * 32;
    if (kh == 2) {
#pragma unroll
      for (int i = 0; i < 4; ++i) {
        f32x4v t = {O0[4 * i], O0[4 * i + 1], O0[4 * i + 2], O0[4 * i + 3]};
        *(f32x4v*)&Ex[sl + 4 * i] = t;
      }
#pragma unroll
      for (int i = 0; i < 4; ++i) {
        f32x4v t = {O1[4 * i], O1[4 * i + 1], O1[4 * i + 2], O1[4 * i + 3]};
        *(f32x4v*)&Ex[sl + 16 + 4 * i] = t;
      }
      Lx[idx] = Lred;
    }
    __syncthreads();
    if (kh == 0) {
#pragma unroll
      for (int i = 0; i < 4; ++i) {
        f32x4v t = *(const f32x4v*)&Ex[sl + 4 * i];
#pragma unroll
        for (int c = 0; c < 4; ++c) O0[4 * i + c] += t[c];
      }
#pragma unroll
      for (int i = 0; i < 4; ++i) {
        f32x4v t = *(const f32x4v*)&Ex[sl + 16 + 4 * i];
#pragma unroll
        for (int c = 0; c < 4; ++c) O1[4 * i + c] += t[c];
      }
      inv = 1.0f / (Lred + Lx[idx]);
    }
    __syncthreads();   // all stage-B reads done before T overwrites lds
  }
  __bf16* T = (__bf16*)lds;                  // [128][72] bf16 = 18,432 B
  if (kh == 0) {
#pragma unroll
    for (int dh = 0; dh < 2; ++dh) {
#pragma unroll
      for (int a = 0; a < 4; ++a) {
        const f32x16 O = dh ? O1 : O0;
        bf16x4 t4;
#pragma unroll
        for (int c = 0; c < 4; ++c) t4[c] = (__bf16)(O[4 * a + c] * inv);
        *(bf16x4*)&T[((qg * 32 + ln)) * 72 + dh * 32 + 8 * a + 4 * g] = t4;
      }
    }
  }
  __syncthreads();
  // coalesced tiled store: 1024 thr cover 128 rows x 8 col-groups
  {
    const int rq = tid >> 3;                 // 0..127
    const int c8 = (tid & 7) * 8;
    bf16x8 o = *(const bf16x8*)&T[rq * 72 + c8];
    const int m = bz * Sn + qb * 128 + rq;
    const int kg = h * 8 + (tid & 7);
    size_t base = ((size_t)(m >> 5) * 128 + kg) * 256 + (m & 31) * 8;
    *(bf16x8*)&Cc[base] = o;
  }
#undef STAGE
}

// ---------------------------------------------------------------- projection
// out(4096,1024) = concat @ W + b. ZERO-LDS, zero-barrier, TILED fragment
// layouts (A=Cc, W=Wt): a wave's (ln,g) 16B loads = 1KB contiguous.
// XCD-chunked map (r15). 128x64 tile, 8 waves = mq{0..3} x nh{0,1}.
__global__ __launch_bounds__(512, 4) void proj(
    const __bf16* __restrict__ A2, const __bf16* __restrict__ Wt2,
    const float* __restrict__ bias, float* __restrict__ out) {
  const int tid = threadIdx.x, wave = tid >> 6, lane = tid & 63;
  const int ln = lane & 31, g = lane >> 5;
  const int mq = wave >> 1, nh = wave & 1;
  const int f = blockIdx.x;
  const int idx = f >> 3;
  const int bn = idx & 15;
  const int bm = (f & 7) * 4 + (idx >> 4);

  const int mg = bm * 4 + mq;                // 32-row group of A
  const int ng = bn * 2 + nh;                // 32-row group of W^T
  const __bf16* Ab = A2  + (size_t)mg * 128 * 256 + (size_t)ln * 8;
  const __bf16* Wb = Wt2 + (size_t)ng * 128 * 256 + (size_t)ln * 8;

  f32x16 acc = {};
#pragma unroll 4
  for (int kt = 0; kt < 16; ++kt) {
#pragma unroll
    for (int ks = 0; ks < 4; ++ks) {
      const size_t off = (size_t)(kt * 8 + ks * 2 + g) * 256;
      bf16x8 af = *(const bf16x8*)(Ab + off);
      bf16x8 wf = *(const bf16x8*)(Wb + off);
      acc = __builtin_amdgcn_mfma_f32_32x32x16_bf16(af, wf, acc, 0, 0, 0);
    }
  }
  const float bv = bias[bn * 64 + nh * 32 + ln];
#pragma unroll
  for (int r = 0; r < 16; ++r) {
    int row = bm * 128 + mq * 32 + (r & 3) + 8 * (r >> 2) + 4 * g;
    out[(size_t)row * DM + bn * 64 + nh * 32 + ln] = acc[r] + bv;
  }
}

// ---------------------------------------------------------------- launch
extern "C" void kernel_launch(void* const* d_in, const int* in_sizes, int n_in,
                              void* d_out, int out_size, void* d_ws, size_t ws_size,
                              hipStream_t stream) {
  const float* Q = (const float*)d_in[0];
  const float* K = (const float*)d_in[1];
  const float* V = (const float*)d_in[2];
  const float* W = (const float*)d_in[3];
  const float* b = (const float*)d_in[4];
  float* out = (float*)d_out;

  __bf16* ws  = (__bf16*)d_ws;
  __bf16* Vtg = ws;                           // (b,h,d,kv) bf16
  __bf16* Cc  = Vtg + QKV_ELEMS;              // concat, TILED frag layout
  __bf16* Wt  = Cc + QKV_ELEMS;               // W^T, TILED frag layout

  convert_vw<<<dim3(1280, 1, 1), 256, 0, stream>>>(V, W, Vtg, Wt);
  attn<<<dim3(512, 1, 1), 1024, 0, stream>>>(Q, K, Vtg, Cc);
  proj<<<dim3(512, 1, 1), 512, 0, stream>>>(Cc, Wt, b, out);
}

// Round 11
// 155.688 us; speedup vs baseline: 2.7014x; 2.7014x over previous
//
#include <hip/hip_runtime.h>
#include <hip/hip_bf16.h>

// B=2, H=16, S=2048, D=64, DMODEL=1024
// Round 21: r20's forced-occupancy bet spilled (VGPR 32, 1.3GB scratch,
// 334us) -> 32 w/CU is unreachable for this loop's live state; 16 w/CU @
// ~52us is the practical optimum (8 w/CU costs +16us, r19). Consolidate:
// base = r15 VERBATIM (best total 152.5) + the one safe, attributable
// delta: K fp32->bf16 fusion into attn staging (r18 proved fusion ~free;
// deletes 2048 of 3328 convert blocks + K's 16MB read/8MB write). Tiled
// proj dropped (r17: no gain). Fill floor 82us is harness-fixed (r18 diag).
// Budget: fills 82 + attn ~53 + convert_vw ~7 + proj ~12 ~= 154 -> predict
// ~146-150 total.

typedef float  f32x16 __attribute__((ext_vector_type(16)));
typedef float  f32x4v __attribute__((ext_vector_type(4)));
typedef float  f32x2v __attribute__((ext_vector_type(2)));
typedef __bf16 bf16x8 __attribute__((ext_vector_type(8)));
typedef __bf16 bf16x4 __attribute__((ext_vector_type(4)));
typedef __bf16 bf16x2 __attribute__((ext_vector_type(2)));

static constexpr int Bn = 2, Hn = 16, Sn = 2048, Dn = 64, DM = 1024;
static constexpr size_t QKV_ELEMS = (size_t)Bn * Hn * Sn * Dn;   // 4,194,304

#define QSCALE 0.18033688011112042f   // 0.125 * log2(e)

// lgkm-only barrier: LDS writes drained, global prefetch stays in flight.
#define LGKM_BARRIER() do {                                  \
    asm volatile("s_waitcnt lgkmcnt(0)" ::: "memory");       \
    __builtin_amdgcn_s_barrier();                            \
  } while (0)

#if __has_builtin(__builtin_amdgcn_cvt_pk_bf16_f32)
static __device__ __forceinline__ unsigned pack2(float a, float b) {
  bf16x2 t = __builtin_amdgcn_cvt_pk_bf16_f32(a, b);
  union { bf16x2 v; unsigned u; } c; c.v = t; return c.u;
}
#else
static __device__ __forceinline__ unsigned pack2(float a, float b) {
  union { __bf16 h; unsigned short s; } ua, ub;
  ua.h = (__bf16)a; ub.h = (__bf16)b;
  return (unsigned)ua.s | ((unsigned)ub.s << 16);
}
#endif

static __device__ __forceinline__ void unzip8(const unsigned* wds, bf16x8* r0, bf16x8* r1) {
  union { unsigned u[4]; bf16x8 v; } a, b;
#pragma unroll
  for (int i = 0; i < 4; ++i) {
    unsigned lo = wds[2 * i], hi = wds[2 * i + 1];
    a.u[i] = (lo & 0xffffu) | (hi << 16);
    b.u[i] = (lo >> 16) | (hi & 0xffff0000u);
  }
  *r0 = a.v; *r1 = b.v;
}

// ------------------------------------------------- V-T + W-T converts only
// [0,1024) V-T; [1024,1280) W-T (plain [n][k]). K fused into attn.
__global__ __launch_bounds__(256) void convert_vw(
    const float* __restrict__ v, const float* __restrict__ w,
    __bf16* __restrict__ vt, __bf16* __restrict__ wt) {
  __shared__ __bf16 T[64][74];
  const int bid = blockIdx.x, t = threadIdx.x;

  const float* s0;
  __bf16* dst0;
  size_t dst_stride;
  {
    const int r = t >> 2, c0 = (t & 3) * 16;
    if (bid < 1024) {
      const int idx = bid;
      const int kv0 = (idx & 31) * 64, bh = idx >> 5;
      s0 = v + ((size_t)bh * Sn + kv0 + r) * Dn + c0;
      dst0 = vt + (size_t)bh * Dn * Sn + kv0;
      dst_stride = Sn;
    } else {
      const int idx = bid - 1024;
      const int nt = (idx & 15) * 64, kt = (idx >> 4) * 64;
      s0 = w + (size_t)(kt + r) * DM + nt + c0;
      dst0 = wt + (size_t)nt * DM + kt;
      dst_stride = DM;
    }
    union { bf16x8 v8; unsigned u[4]; } o0, o1;
#pragma unroll
    for (int i = 0; i < 2; ++i) {
      f32x4v f = *(const f32x4v*)(s0 + i * 4);
#pragma unroll
      for (int j = 0; j < 4; ++j) o0.v8[i * 4 + j] = (__bf16)f[j];
    }
#pragma unroll
    for (int i = 0; i < 2; ++i) {
      f32x4v f = *(const f32x4v*)(s0 + 8 + i * 4);
#pragma unroll
      for (int j = 0; j < 4; ++j) o1.v8[i * 4 + j] = (__bf16)f[j];
    }
#pragma unroll
    for (int j = 0; j < 4; ++j) {
      *(unsigned*)&T[r][c0 + 2 * j]     = o0.u[j];
      *(unsigned*)&T[r][c0 + 8 + 2 * j] = o1.u[j];
    }
  }
  __syncthreads();
  const int rp = t >> 3, k0 = (t & 7) * 8;
  unsigned wds[8];
#pragma unroll
  for (int i = 0; i < 8; ++i) wds[i] = *(const unsigned*)&T[k0 + i][2 * rp];
  bf16x8 r0, r1; unzip8(wds, &r0, &r1);
  __bf16* d0 = dst0 + (size_t)(2 * rp) * dst_stride + k0;
  *(bf16x8*)d0 = r0;
  *(bf16x8*)(d0 + dst_stride) = r1;
}

// ---------------------------------------------------------------- attention
// r15 structure (proven 53us): 512 blocks XCD-chunked, 8 waves = (qg x 32q,
// kh x 64kv-half), KVBLK=128, dbuf, 1 lgkm-barrier/iter. K read fp32 and
// converted in-register during staging (fusion, r18-verified mechanics).
__global__ __launch_bounds__(512, 4) void attn(
    const float* __restrict__ Qf, const float* __restrict__ Kf,
    const __bf16* __restrict__ Vtg, __bf16* __restrict__ Cc) {
  const int tid = threadIdx.x;
  const int wave = tid >> 6, lane = tid & 63;
  const int ln = lane & 31, g = lane >> 5;
  const int qg = wave >> 1, kh = wave & 1;
  // XCD-chunked bijective swizzle (verified r14/r15): f&7 = XCD.
  const int f = blockIdx.x;
  const int swz = (f & 7) * 64 + (f >> 3);
  const int qb = swz & 15, h = (swz >> 4) & 15, bz = swz >> 8;

  __shared__ __bf16 Ks[2][128][72];          // 36864 B
  __shared__ __bf16 Vs[2][64][136];          // 34816 B -> 71680 total, 2 blk/CU

  const size_t hoff = (size_t)(bz * Hn + h) * Sn * Dn;
  const float*  Qp = Qf + hoff + (size_t)(qb * 128 + qg * 32) * Dn;
  const float*  Kp = Kf + hoff;      // fp32 [kv][d]
  const __bf16* Vp = Vtg + hoff;     // bf16 [d][kv]

  // Q A-fragments: fp32 load + scale + cvt (prologue only)
  bf16x8 qf[4];
#pragma unroll
  for (int ks = 0; ks < 4; ++ks) {
    const float* qp = Qp + (size_t)ln * Dn + ks * 16 + g * 8;
    f32x4v f0 = *(const f32x4v*)qp;
    f32x4v f1 = *(const f32x4v*)(qp + 4);
#pragma unroll
    for (int j = 0; j < 4; ++j) {
      qf[ks][j]     = (__bf16)(f0[j] * QSCALE);
      qf[ks][4 + j] = (__bf16)(f1[j] * QSCALE);
    }
  }

  // staging maps: K tile [128 kv][64 d] fp32 (16 floats/thread),
  // V tile [64 d][128 kv] (2 b128/thread, permuted write)
  const int kr = tid >> 2, kc = (tid & 3) * 16;
  const int vr = tid >> 3, vc = (tid & 7) * 16;
  const float*  kbasef = Kp + (size_t)kr * Dn + kc;
  const __bf16* vbase  = Vp + (size_t)vr * Sn + vc;

  // stage tile 0 (convert K in-register), then prefetch tile 1 into regs
  f32x4v ka0, ka1, ka2, ka3;
  bf16x8 v0r, v1r;
  {
    ka0 = *(const f32x4v*)(kbasef);
    ka1 = *(const f32x4v*)(kbasef + 4);
    ka2 = *(const f32x4v*)(kbasef + 8);
    ka3 = *(const f32x4v*)(kbasef + 12);
    bf16x8 kx0, kx1;
#pragma unroll
    for (int j = 0; j < 4; ++j) {
      kx0[j] = (__bf16)ka0[j]; kx0[4 + j] = (__bf16)ka1[j];
      kx1[j] = (__bf16)ka2[j]; kx1[4 + j] = (__bf16)ka3[j];
    }
    *(bf16x8*)&Ks[0][kr][kc]     = kx0;
    *(bf16x8*)&Ks[0][kr][kc + 8] = kx1;
    v0r = *(const bf16x8*)vbase; v1r = *(const bf16x8*)(vbase + 8);
    union { bf16x8 v; bf16x4 h[2]; } u0, u1; u0.v = v0r; u1.v = v1r;
    union { bf16x4 h[2]; bf16x8 v; } w0, w1;
    w0.h[0] = u0.h[0]; w0.h[1] = u1.h[0];
    w1.h[0] = u0.h[1]; w1.h[1] = u1.h[1];
    *(bf16x8*)&Vs[0][vr][vc]     = w0.v;
    *(bf16x8*)&Vs[0][vr][vc + 8] = w1.v;
  }
  ka0 = *(const f32x4v*)(kbasef + (size_t)128 * Dn);
  ka1 = *(const f32x4v*)(kbasef + (size_t)128 * Dn + 4);
  ka2 = *(const f32x4v*)(kbasef + (size_t)128 * Dn + 8);
  ka3 = *(const f32x4v*)(kbasef + (size_t)128 * Dn + 12);
  v0r = *(const bf16x8*)(vbase + 128);
  v1r = *(const bf16x8*)(vbase + 128 + 8);
  LGKM_BARRIER();

  f32x16 O0 = {}, O1 = {};                   // O^T halves: d in [0,32),[32,64)
  float Lown = 0.0f;
  constexpr int NT = Sn / 128;               // 16

  for (int kt = 0; kt < NT; ++kt) {
    const int buf = kt & 1;

    // QK^T + softmax-exp in two m-halves (kv 32-row blocks of this kh half)
    unsigned w[16];
#pragma unroll
    for (int m = 0; m < 2; ++m) {
      bf16x8 kf[4];
#pragma unroll
      for (int ks = 0; ks < 4; ++ks)
        kf[ks] = *(const bf16x8*)&Ks[buf][kh * 64 + m * 32 + ln][ks * 16 + g * 8];

      f32x16 s = {};
      __builtin_amdgcn_s_setprio(1);
#pragma unroll
      for (int ks = 0; ks < 4; ++ks)
        s = __builtin_amdgcn_mfma_f32_32x32x16_bf16(kf[ks], qf[ks], s, 0, 0, 0);
      __builtin_amdgcn_s_setprio(0);

      float p[16];
#pragma unroll
      for (int r = 0; r < 16; ++r) p[r] = __builtin_amdgcn_exp2f(s[r]);
      f32x2v s2 = {0.0f, 0.0f};
#pragma unroll
      for (int tt = 0; tt < 8; ++tt) { f32x2v t2 = {p[2 * tt], p[2 * tt + 1]}; s2 += t2; }
      Lown += s2[0] + s2[1];
#pragma unroll
      for (int tt = 0; tt < 8; ++tt) w[m * 8 + tt] = pack2(p[2 * tt], p[2 * tt + 1]);
    }

    if (kt + 1 < NT) {
      const int nb = buf ^ 1;
      bf16x8 kx0, kx1;
#pragma unroll
      for (int j = 0; j < 4; ++j) {
        kx0[j] = (__bf16)ka0[j]; kx0[4 + j] = (__bf16)ka1[j];
        kx1[j] = (__bf16)ka2[j]; kx1[4 + j] = (__bf16)ka3[j];
      }
      *(bf16x8*)&Ks[nb][kr][kc]     = kx0;
      *(bf16x8*)&Ks[nb][kr][kc + 8] = kx1;
      union { bf16x8 v; bf16x4 h[2]; } u0, u1; u0.v = v0r; u1.v = v1r;
      union { bf16x4 h[2]; bf16x8 v; } w0, w1;
      w0.h[0] = u0.h[0]; w0.h[1] = u1.h[0];
      w1.h[0] = u0.h[1]; w1.h[1] = u1.h[1];
      *(bf16x8*)&Vs[nb][vr][vc]     = w0.v;
      *(bf16x8*)&Vs[nb][vr][vc + 8] = w1.v;
      if (kt + 2 < NT) {
        const float* kp = kbasef + (size_t)(kt + 2) * 128 * Dn;
        ka0 = *(const f32x4v*)kp;       ka1 = *(const f32x4v*)(kp + 4);
        ka2 = *(const f32x4v*)(kp + 8); ka3 = *(const f32x4v*)(kp + 12);
        const __bf16* vp = vbase + (kt + 2) * 128;
        v0r = *(const bf16x8*)vp; v1r = *(const bf16x8*)(vp + 8);
      }
    }

    // PV over this wave's 64-kv half: 4 k-slices; permuted V^T supplies each
    // 8-kv group as ONE contiguous b128 at col kh*64 + s4*16 + g*8.
    __builtin_amdgcn_s_setprio(1);
#pragma unroll
    for (int s4 = 0; s4 < 4; ++s4) {
      const int cb = kh * 64 + s4 * 16 + g * 8;
      bf16x8 vf0 = *(const bf16x8*)&Vs[buf][ln][cb];
      bf16x8 vf1 = *(const bf16x8*)&Vs[buf][32 + ln][cb];
      union { unsigned u[4]; bf16x8 v; } pu;
      pu.u[0] = w[s4 * 4 + 0];
      pu.u[1] = w[s4 * 4 + 1];
      pu.u[2] = w[s4 * 4 + 2];
      pu.u[3] = w[s4 * 4 + 3];
      O0 = __builtin_amdgcn_mfma_f32_32x32x16_bf16(vf0, pu.v, O0, 0, 0, 0);
      O1 = __builtin_amdgcn_mfma_f32_32x32x16_bf16(vf1, pu.v, O1, 0, 0, 0);
    }
    __builtin_amdgcn_s_setprio(0);

    LGKM_BARRIER();
  }

  // ---- kh pair-reduction via LDS; normalize; transpose; coalesced store ----
  const float Lred = Lown + __shfl_xor(Lown, 32);
  float* Ex = (float*)Ks;                    // 256 slots x 36 f32 = 36864 B
  const int slot = (qg * 64 + lane) * 36;
  if (kh == 1) {
#pragma unroll
    for (int i = 0; i < 4; ++i) {
      f32x4v t = {O0[4 * i], O0[4 * i + 1], O0[4 * i + 2], O0[4 * i + 3]};
      *(f32x4v*)&Ex[slot + 4 * i] = t;
    }
#pragma unroll
    for (int i = 0; i < 4; ++i) {
      f32x4v t = {O1[4 * i], O1[4 * i + 1], O1[4 * i + 2], O1[4 * i + 3]};
      *(f32x4v*)&Ex[slot + 16 + 4 * i] = t;
    }
    Ex[slot + 32] = Lred;
  }
  __syncthreads();
  __bf16* T = (__bf16*)Vs;                   // [128][72] bf16 = 18432 B
  if (kh == 0) {
    float inv;
#pragma unroll
    for (int i = 0; i < 4; ++i) {
      f32x4v t = *(const f32x4v*)&Ex[slot + 4 * i];
#pragma unroll
      for (int c = 0; c < 4; ++c) O0[4 * i + c] += t[c];
    }
#pragma unroll
    for (int i = 0; i < 4; ++i) {
      f32x4v t = *(const f32x4v*)&Ex[slot + 16 + 4 * i];
#pragma unroll
      for (int c = 0; c < 4; ++c) O1[4 * i + c] += t[c];
    }
    inv = 1.0f / (Lred + Ex[slot + 32]);
#pragma unroll
    for (int dh = 0; dh < 2; ++dh) {
#pragma unroll
      for (int a = 0; a < 4; ++a) {
        const f32x16 O = dh ? O1 : O0;
        bf16x4 t4;
#pragma unroll
        for (int c = 0; c < 4; ++c) t4[c] = (__bf16)(O[4 * a + c] * inv);
        *(bf16x4*)&T[(qg * 32 + ln) * 72 + dh * 32 + 8 * a + 4 * g] = t4;
      }
    }
  }
  __syncthreads();
  const int q0 = qb * 128;
#pragma unroll
  for (int i = 0; i < 2; ++i) {
    const int rq = i * 64 + (tid >> 3);
    const int c8 = (tid & 7) * 8;
    bf16x8 o = *(const bf16x8*)&T[rq * 72 + c8];
    size_t base = (((size_t)bz * Sn + q0 + rq) * Hn + h) * Dn + c8;
    *(bf16x8*)&Cc[base] = o;
  }
}

// ---------------------------------------------------------------- projection
// out(4096,1024) = concat @ W + b. 128x64 tile, 512 threads = 8 waves,
// dbuf, one barrier/iter. XCD-chunked block map (r15-proven): per XCD
// working set = A panel 1MB + W 2MB <= 4MB L2.
__global__ __launch_bounds__(512, 2) void proj(
    const __bf16* __restrict__ A, const __bf16* __restrict__ Wt,
    const float* __restrict__ bias, float* __restrict__ out) {
  const int tid = threadIdx.x, wave = tid >> 6, lane = tid & 63;
  const int ln = lane & 31, g = lane >> 5;
  const int mq = wave >> 1, nh = wave & 1;
  const int f = blockIdx.x;
  const int idx = f >> 3;
  const int bn = idx & 15;
  const int bm = (f & 7) * 4 + (idx >> 4);
  __shared__ __bf16 As[2][128][72];
  __shared__ __bf16 Bs[2][64][72];
  const int ar = tid >> 2, ac = (tid & 3) * 16;   // A: 2 b128/thread
  const int rb = tid >> 3, cb = (tid & 7) * 8;    // B: 1 b128/thread
  f32x16 acc = {};
  const __bf16* Ap = A + (size_t)(bm * 128) * DM;
  const __bf16* Wp = Wt + (size_t)(bn * 64) * DM;

  bf16x8 a0, a1, b0;
  {
    const __bf16* ap = Ap + (size_t)ar * DM + ac;
    a0 = *(const bf16x8*)ap; a1 = *(const bf16x8*)(ap + 8);
    b0 = *(const bf16x8*)(Wp + (size_t)rb * DM + cb);
  }
  *(bf16x8*)&As[0][ar][ac]     = a0;
  *(bf16x8*)&As[0][ar][ac + 8] = a1;
  *(bf16x8*)&Bs[0][rb][cb]     = b0;
  {
    const __bf16* ap = Ap + (size_t)ar * DM + 64 + ac;
    a0 = *(const bf16x8*)ap; a1 = *(const bf16x8*)(ap + 8);
    b0 = *(const bf16x8*)(Wp + (size_t)rb * DM + 64 + cb);
  }
  LGKM_BARRIER();

  constexpr int KT = DM / 64;
  for (int kt = 0; kt < KT; ++kt) {
    const int buf = kt & 1;
    __builtin_amdgcn_s_setprio(1);
#pragma unroll
    for (int ks = 0; ks < 4; ++ks) {
      bf16x8 af = *(const bf16x8*)&As[buf][mq * 32 + ln][ks * 16 + g * 8];
      bf16x8 wf = *(const bf16x8*)&Bs[buf][nh * 32 + ln][ks * 16 + g * 8];
      acc = __builtin_amdgcn_mfma_f32_32x32x16_bf16(af, wf, acc, 0, 0, 0);
    }
    __builtin_amdgcn_s_setprio(0);
    if (kt + 1 < KT) {
      const int nb = buf ^ 1;
      *(bf16x8*)&As[nb][ar][ac]     = a0;
      *(bf16x8*)&As[nb][ar][ac + 8] = a1;
      *(bf16x8*)&Bs[nb][rb][cb]     = b0;
      if (kt + 2 < KT) {
        const __bf16* ap = Ap + (size_t)ar * DM + (kt + 2) * 64 + ac;
        a0 = *(const bf16x8*)ap; a1 = *(const bf16x8*)(ap + 8);
        b0 = *(const bf16x8*)(Wp + (size_t)rb * DM + (kt + 2) * 64 + cb);
      }
    }
    LGKM_BARRIER();
  }
  const float bv = bias[bn * 64 + nh * 32 + ln];
#pragma unroll
  for (int r = 0; r < 16; ++r) {
    int row = bm * 128 + mq * 32 + (r & 3) + 8 * (r >> 2) + 4 * g;
    out[(size_t)row * DM + bn * 64 + nh * 32 + ln] = acc[r] + bv;
  }
}

// ---------------------------------------------------------------- launch
extern "C" void kernel_launch(void* const* d_in, const int* in_sizes, int n_in,
                              void* d_out, int out_size, void* d_ws, size_t ws_size,
                              hipStream_t stream) {
  const float* Q = (const float*)d_in[0];
  const float* K = (const float*)d_in[1];
  const float* V = (const float*)d_in[2];
  const float* W = (const float*)d_in[3];
  const float* b = (const float*)d_in[4];
  float* out = (float*)d_out;

  __bf16* ws  = (__bf16*)d_ws;
  __bf16* Vtg = ws;                           // (b,h,d,kv) bf16
  __bf16* Cc  = Vtg + QKV_ELEMS;              // concat (B,S,H,D) bf16
  __bf16* Wt  = Cc + QKV_ELEMS;               // (n,k) bf16

  convert_vw<<<dim3(1280, 1, 1), 256, 0, stream>>>(V, W, Vtg, Wt);
  attn<<<dim3(512, 1, 1), 512, 0, stream>>>(Q, K, Vtg, Cc);
  proj<<<dim3(512, 1, 1), 512, 0, stream>>>(Cc, Wt, b, out);
}